// Round 3
// baseline (63.860 us; speedup 1.0000x reference)
//
#include <hip/hip_runtime.h>
#include <math.h>

#define WIDTH 8192
#define NROW  2048          // B*C = 16*128
#define T4    (WIDTH / 4)   // float4 slots per row = 2048

// ---------------------------------------------------------------------------
// Probe: decide how the boolean mask was marshalled.
//   flag = 0 : int32 per element, 1 : byte per element, 2 : float32 per elem
// ---------------------------------------------------------------------------
__global__ void detect_mask_kind(const unsigned* __restrict__ mw,
                                 int* __restrict__ flag) {
    int lid = threadIdx.x;  // one wave of 64
    int isbyte = 0, isfloat = 0;
#pragma unroll
    for (int j = 0; j < 4; ++j) {
        unsigned w = mw[lid * 4 + j];
        if (w == 0x3F800000u)      isfloat = 1;
        else if (w > 1u)           isbyte  = 1;
    }
    unsigned long long bf = __ballot(isfloat != 0);
    unsigned long long bb = __ballot(isbyte != 0);
    if (lid == 0) flag[0] = bf ? 2 : (bb ? 1 : 0);
}

// compare-exchange: a=min, b=max
#define CE(a, b) { float _lo = fminf(a, b); float _hi = fmaxf(a, b); (a) = _lo; (b) = _hi; }

// median of merge(sorted A[4], sorted tail T[3]) at index k=(n-1)>>1 (k<=3).
// M[k] = min over i+j=k of max(A[i], T[j])  (out-of-range -> +inf, index -1 -> -inf)
#define MEDIAN(A0,A1,A2,A3, T0,T1,T2, N, DST) {                                   \
    float _M0 = fminf(A0, T0);                                                    \
    float _M1 = fminf(fminf(A1, T1), fmaxf(A0, T0));                              \
    float _M2 = fminf(fminf(A2, T2), fminf(fmaxf(A1, T0), fmaxf(A0, T1)));        \
    float _M3 = fminf(fminf(A3, fmaxf(A2, T0)),                                   \
                      fminf(fmaxf(A1, T1), fmaxf(A0, T2)));                       \
    int   _k  = ((N) - 1) >> 1;                                                   \
    float _md = (_k <= 0) ? _M0 : (_k == 1) ? _M1 : (_k == 2) ? _M2 : _M3;        \
    (DST) = (_md == INF) ? __builtin_nanf("") : _md; }

__launch_bounds__(256)
__global__ void mmp_kernel(const float* __restrict__ x,
                           const void* __restrict__ mask,
                           const int* __restrict__ flag,
                           float* __restrict__ out) {
    const int bid   = blockIdx.x;
    const int row   = bid >> 2;                 // 4 blocks per row
    const int chunk = bid & 3;
    const int o0    = chunk * 2048 + threadIdx.x * 8;   // first of 8 outputs
    const int t     = o0 >> 2;                  // first of 2 output float4 slots
    const long rb4  = (long)row * T4;           // row base in float4 slots

    // ---- x: 16 values covering original indices o0-4 .. o0+11 ----
    const float4* x4 = (const float4*)x + rb4;
    const float4 Z4  = make_float4(0.f, 0.f, 0.f, 0.f);
    float4 X0 = (t > 0)      ? x4[t - 1] : Z4;
    float4 X1 = x4[t];
    float4 X2 = x4[t + 1];
    float4 X3 = (t + 2 < T4) ? x4[t + 2] : Z4;

    const float xv[16] = { X0.x, X0.y, X0.z, X0.w,  X1.x, X1.y, X1.z, X1.w,
                           X2.x, X2.y, X2.z, X2.w,  X3.x, X3.y, X3.z, X3.w };

    // ---- validity bits bv[1..14] (element j = original index o0-4+j) ----
    unsigned bv[16];
    const int kind = flag[0];                   // uniform branch
    if (kind == 1) {                            // byte mask (numpy bool_)
        const unsigned* mw = (const unsigned*)mask + rb4;
        unsigned wz[4];
        wz[0] = (t > 0)      ? mw[t - 1] : 0u;
        wz[1] = mw[t];
        wz[2] = mw[t + 1];
        wz[3] = (t + 2 < T4) ? mw[t + 2] : 0u;
#pragma unroll
        for (int j = 1; j <= 14; ++j) {
            unsigned b = (wz[j >> 2] >> (8 * (j & 3))) & 0xFFu;
            bv[j] = (b < 1u) ? b : 1u;          // v_min_u32
        }
    } else if (kind == 0) {                     // int32 mask
        const int4* m4 = (const int4*)mask + rb4;
        const int4 ZI = make_int4(0, 0, 0, 0);
        int4 I0 = (t > 0)      ? m4[t - 1] : ZI;
        int4 I1 = m4[t];
        int4 I2 = m4[t + 1];
        int4 I3 = (t + 2 < T4) ? m4[t + 2] : ZI;
        const int iv[16] = { I0.x, I0.y, I0.z, I0.w,  I1.x, I1.y, I1.z, I1.w,
                             I2.x, I2.y, I2.z, I2.w,  I3.x, I3.y, I3.z, I3.w };
#pragma unroll
        for (int j = 1; j <= 14; ++j) bv[j] = (iv[j] != 0) ? 1u : 0u;
    } else {                                    // float32 mask
        const float4* m4 = (const float4*)mask + rb4;
        float4 F0 = (t > 0)      ? m4[t - 1] : Z4;
        float4 F1 = m4[t];
        float4 F2 = m4[t + 1];
        float4 F3 = (t + 2 < T4) ? m4[t + 2] : Z4;
        const float fv[16] = { F0.x, F0.y, F0.z, F0.w,  F1.x, F1.y, F1.z, F1.w,
                               F2.x, F2.y, F2.z, F2.w,  F3.x, F3.y, F3.z, F3.w };
#pragma unroll
        for (int j = 1; j <= 14; ++j) bv[j] = (fv[j] != 0.f) ? 1u : 0u;
    }

    const float INF = __builtin_inff();

    // ---- masked values, built ONCE, shared by all 8 windows ----
    float m[16];
#pragma unroll
    for (int j = 1; j <= 14; ++j) m[j] = bv[j] ? xv[j] : INF;

    // ---- shared sorted pairs ----
    float l23 = m[2],  h23 = m[3];   CE(l23, h23);
    float l67 = m[6],  h67 = m[7];   CE(l67, h67);
    float l89 = m[8],  h89 = m[9];   CE(l89, h89);
    float l1213 = m[12], h1213 = m[13]; CE(l1213, h1213);

    // ---- core A = sorted {m4,m5,m6,m7} (reuses pair67) ----
    float A0 = m[4], A1 = m[5]; CE(A0, A1);
    float A2 = l67,  A3 = h67;
    CE(A0, A2); CE(A1, A3); CE(A1, A2);

    // ---- core B = sorted {m8,m9,m10,m11} (reuses pair89) ----
    float B2 = m[10], B3 = m[11]; CE(B2, B3);
    float B0 = l89,   B1 = h89;
    CE(B0, B2); CE(B1, B3); CE(B1, B2);

    // ---- sorted tails (insert into shared pairs, 2 CE each) ----
    float u0 = m[1], u1 = l23, u2 = h23;  CE(u0, u1); CE(u1, u2);     // W0 {1,2,3}
    float v0 = l23,  v1 = h23, v2 = m[8]; CE(v1, v2); CE(v0, v1);     // W1 {2,3,8}
    float q0 = m[3], q1 = l89, q2 = h89;  CE(q0, q1); CE(q1, q2);     // W2 {3,8,9}
    float r0 = l89,  r1 = h89, r2 = m[10]; CE(r1, r2); CE(r0, r1);    // W3 {8,9,10}
    float s0 = m[5], s1 = l67, s2 = h67;  CE(s0, s1); CE(s1, s2);     // W4 {5,6,7}
    float p0 = l67,  p1 = h67, p2 = m[12]; CE(p1, p2); CE(p0, p1);    // W5 {6,7,12}
    float g0 = m[7], g1 = l1213, g2 = h1213; CE(g0, g1); CE(g1, g2);  // W6 {7,12,13}
    float e0 = l1213, e1 = h1213, e2 = m[14]; CE(e1, e2); CE(e0, e1); // W7 {12,13,14}

    // ---- valid counts per window (sliding sums of 0/1 bits) ----
    int n0 = (int)(bv[1] + bv[2] + bv[3] + bv[4] + bv[5] + bv[6] + bv[7]);
    int n1 = n0 - (int)bv[1] + (int)bv[8];
    int n2 = n1 - (int)bv[2] + (int)bv[9];
    int n3 = n2 - (int)bv[3] + (int)bv[10];
    int n4 = n3 - (int)bv[4] + (int)bv[11];
    int n5 = n4 - (int)bv[5] + (int)bv[12];
    int n6 = n5 - (int)bv[6] + (int)bv[13];
    int n7 = n6 - (int)bv[7] + (int)bv[14];

    // ---- medians ----
    float o_0, o_1, o_2, o_3, o_4, o_5, o_6, o_7;
    MEDIAN(A0, A1, A2, A3, u0, u1, u2, n0, o_0);
    MEDIAN(A0, A1, A2, A3, v0, v1, v2, n1, o_1);
    MEDIAN(A0, A1, A2, A3, q0, q1, q2, n2, o_2);
    MEDIAN(A0, A1, A2, A3, r0, r1, r2, n3, o_3);
    MEDIAN(B0, B1, B2, B3, s0, s1, s2, n4, o_4);
    MEDIAN(B0, B1, B2, B3, p0, p1, p2, n5, o_5);
    MEDIAN(B0, B1, B2, B3, g0, g1, g2, n6, o_6);
    MEDIAN(B0, B1, B2, B3, e0, e1, e2, n7, o_7);

    float4* o4 = (float4*)out + rb4;
    o4[t]     = make_float4(o_0, o_1, o_2, o_3);
    o4[t + 1] = make_float4(o_4, o_5, o_6, o_7);
}

extern "C" void kernel_launch(void* const* d_in, const int* in_sizes, int n_in,
                              void* d_out, int out_size, void* d_ws, size_t ws_size,
                              hipStream_t stream) {
    const float* x    = (const float*)d_in[0];
    const void*  mask = d_in[1];
    int*   flag = (int*)d_ws;
    float* outp = (float*)d_out;

    detect_mask_kind<<<1, 64, 0, stream>>>((const unsigned*)mask, flag);
    mmp_kernel<<<NROW * 4, 256, 0, stream>>>(x, mask, flag, outp);
}